// Round 20
// baseline (87.790 us; speedup 1.0000x reference)
//
#include <hip/hip_runtime.h>
#include <hip/hip_bf16.h>

typedef __attribute__((ext_vector_type(4))) float  floatx4;
typedef __attribute__((ext_vector_type(2))) float  floatx2;
typedef __attribute__((ext_vector_type(8))) __bf16 bf16x8;

#define FP8_MAX 448.0f

// HW OCP e4m3fn round-trip (RNE), matches ml_dtypes float8_e4m3fn for |v|<=448
__device__ __forceinline__ floatx2 fp8_qdq2(float a, float b) {
    int p = __builtin_amdgcn_cvt_pk_fp8_f32(a, b, 0, false);
    return __builtin_amdgcn_cvt_pk_f32_fp8(p, false);
}

__device__ __forceinline__ unsigned int f2bf(float f) {
    union { __hip_bfloat16 h; unsigned short u; } cv;
    cv.h = __float2bfloat16(f);
    return (unsigned int)cv.u;
}

__device__ __forceinline__ void async_copy16(void* lds, const void* g) {
    __builtin_amdgcn_global_load_lds(
        (const __attribute__((address_space(1))) unsigned int*)g,
        (__attribute__((address_space(3))) unsigned int*)lds, 16, 0, 0);
}

// ---------------------------------------------------------------------------
// Kernel 1: dequantize W [D=512][F=512] (quant blocks of 128 along F),
//           write transposed bf16 Wt [F=512][D=512].
__global__ void wdq_kernel(const float* __restrict__ W,
                           __hip_bfloat16* __restrict__ Wt) {
    const int D = 512, F = 512;
    int d = blockIdx.x;
    int t = threadIdx.x;
    float4 v = *reinterpret_cast<const float4*>(W + (size_t)d * F + t * 4);
    float am = fmaxf(fmaxf(fabsf(v.x), fabsf(v.y)), fmaxf(fabsf(v.z), fabsf(v.w)));
#pragma unroll
    for (int s = 16; s >= 1; s >>= 1) am = fmaxf(am, __shfl_xor(am, s));
    float scale = fmaxf(am, 1e-4f) / FP8_MAX;
    floatx2 d01 = fp8_qdq2(v.x / scale, v.y / scale);
    floatx2 d23 = fp8_qdq2(v.z / scale, v.w / scale);
    int f0 = t * 4;
    Wt[(size_t)(f0 + 0) * D + d] = __float2bfloat16(d01[0] * scale);
    Wt[(size_t)(f0 + 1) * D + d] = __float2bfloat16(d01[1] * scale);
    Wt[(size_t)(f0 + 2) * D + d] = __float2bfloat16(d23[0] * scale);
    Wt[(size_t)(f0 + 3) * D + d] = __float2bfloat16(d23[1] * scale);
}

// ---------------------------------------------------------------------------
// Kernel 2 (fused, R16 tile at 2x wave count — the TLP-at-constant-density
// cell rounds 3-19 never tested):
// BM=64/BN=256/BK=64, SAME 80 KB double-buffered LDS, SAME 128 MFMA/block/
// step — but 512 threads = 8 waves (1x8, wave tile 64x32, acc[4][2]) ->
// 16 waves/CU = 4 waves/SIMD (vs R16's 2): cross-wave TLP fills the
// barrier drains (m114) without sacrificing density (R14's mistake).
// Plain __syncthreads every boundary: race-impossible by construction —
// required because __launch_bounds__(512,4) caps VGPR at 128 and a spill
// under counted-vmcnt would corrupt the FIFO count (R13 lesson). Here a
// spill is merely slow, never wrong.
// Quant: 8 thr/row x 16 f32 (shfl_xor 1,2,4); single X stash v[4] (issued
// at odd step t, consumed at t+2); q4 = 2 slots, per-thread data falls in
// ONE k-half (aq<4 -> h0), persists across the h0/h1 writes.
// XOR slot swizzle both-sides (slot ^= row&7): 0 bank conflicts.
__global__ __launch_bounds__(512, 4) void fused_gemm(
        const float* __restrict__ X,             // [M][512] f32
        const __hip_bfloat16* __restrict__ Wt,   // [512 f][512 k] bf16
        const float* __restrict__ bias,          // [512]
        float* __restrict__ C, int M) {
    const int K = 512, N = 512;
    __shared__ char As[2][8192];    // [64 r][8 slot16B], swizzled
    __shared__ char Bs[2][32768];   // [256 f][8 slot16B], swizzled

    // XCD-chunked bijective swizzle (grid 2048 % 8 == 0): tN pair of each tM
    // adjacent on one XCD -> X panel fetched from HBM once.
    int bx   = blockIdx.x;
    int tile = (bx & 7) * (gridDim.x >> 3) + (bx >> 3);
    int tN   = tile & 1;             // N-panel of 256
    int tM   = tile >> 1;            // M-tile of 64 rows

    int tid = threadIdx.x, wid = tid >> 6, lane = tid & 63;
    int wn = wid;                    // wave grid 1(M) x 8(N), tile 64x32
    int lr = lane & 15, lg = lane >> 4;
    int ar = tid >> 3, aq = tid & 7; // A-quant: 8 thr/row, 16 f32 each

    const float* Xb = X + (size_t)(tM * 64) * K;
    const char* Wb  = (const char*)(Wt + (size_t)tN * 256 * K);
    float* Cb = C + (size_t)(tM * 64) * N + tN * 256;

    float4 v[4];        // X stash: 16 f32 of one 128-k quant block slice
    uint4  q4[2];       // quantized bf16 (16 elems = 2 slots, one k-half)
    floatx4 acc[4][2] = {};

    auto loadX = [&](int qb) {
        const float* src = Xb + (size_t)ar * K + qb * 128 + aq * 16;
#pragma unroll
        for (int j = 0; j < 4; ++j)
            v[j] = *reinterpret_cast<const float4*>(src + j * 4);
    };
    auto quantX = [&]() {
        float am = 0.f;
#pragma unroll
        for (int j = 0; j < 4; ++j)
            am = fmaxf(am, fmaxf(fmaxf(fabsf(v[j].x), fabsf(v[j].y)),
                                 fmaxf(fabsf(v[j].z), fabsf(v[j].w))));
        am = fmaxf(am, __shfl_xor(am, 1));
        am = fmaxf(am, __shfl_xor(am, 2));
        am = fmaxf(am, __shfl_xor(am, 4));
        am = fmaxf(am, 1e-4f);
        float scale = am / FP8_MAX;     // exact reference scale (IEEE div)
        float inv   = FP8_MAX / am;
#pragma unroll
        for (int n = 0; n < 2; ++n) {
            floatx2 a0 = fp8_qdq2(v[2*n].x*inv,   v[2*n].y*inv);
            floatx2 a1 = fp8_qdq2(v[2*n].z*inv,   v[2*n].w*inv);
            floatx2 a2 = fp8_qdq2(v[2*n+1].x*inv, v[2*n+1].y*inv);
            floatx2 a3 = fp8_qdq2(v[2*n+1].z*inv, v[2*n+1].w*inv);
            q4[n].x = f2bf(a0[0]*scale) | (f2bf(a0[1]*scale) << 16);
            q4[n].y = f2bf(a1[0]*scale) | (f2bf(a1[1]*scale) << 16);
            q4[n].z = f2bf(a2[0]*scale) | (f2bf(a2[1]*scale) << 16);
            q4[n].w = f2bf(a3[0]*scale) | (f2bf(a3[1]*scale) << 16);
        }
    };
    // Thread's 16 bf16 live entirely in k-half (aq>>2); write its 2 slots.
    auto writeA = [&](int buf, int hb) {
        if ((aq >> 2) == hb) {
#pragma unroll
            for (int n = 0; n < 2; ++n) {
                int slot = (aq & 3) * 2 + n;
                *reinterpret_cast<uint4*>(
                    As[buf] + ar * 128 + ((slot ^ (ar & 7)) << 4)) = q4[n];
            }
        }
    };
    auto stageB = [&](int buf, int step) {   // 32 x 1KB chunks, 4/wave
        const char* base = Wb + step * 128;
#pragma unroll
        for (int cc = 0; cc < 4; ++cc) {
            int c  = wid * 4 + cc;
            int rr = c * 8 + (lane >> 3);
            int d  = lane & 7;
            async_copy16(Bs[buf] + c * 1024,
                         base + (size_t)rr * (K * 2) + ((d ^ (rr & 7)) << 4));
        }
    };
    auto mfmaStep = [&](int buf) {
#pragma unroll
        for (int ks = 0; ks < 2; ++ks) {
            int q = (ks << 2) | lg;
            bf16x8 a[4], b[2];
#pragma unroll
            for (int mi = 0; mi < 4; ++mi) {
                int r = mi * 16 + lr;
                a[mi] = *reinterpret_cast<const bf16x8*>(
                    As[buf] + r * 128 + ((q ^ (r & 7)) << 4));
            }
#pragma unroll
            for (int ni = 0; ni < 2; ++ni) {
                int f = wn * 32 + ni * 16 + lr;
                b[ni] = *reinterpret_cast<const bf16x8*>(
                    Bs[buf] + f * 128 + ((q ^ (f & 7)) << 4));
            }
#pragma unroll
            for (int mi = 0; mi < 4; ++mi)
#pragma unroll
                for (int ni = 0; ni < 2; ++ni)
                    acc[mi][ni] = __builtin_amdgcn_mfma_f32_16x16x32_bf16(
                        a[mi], b[ni], acc[mi][ni], 0, 0, 0);
        }
    };

    // ---- prologue: quant qb0, As[0]=half0, Bs[0]=step0, qb1 in flight ----
    float bv[2];
#pragma unroll
    for (int ni = 0; ni < 2; ++ni)
        bv[ni] = bias[tN * 256 + wn * 32 + ni * 16 + lr];
    loadX(0);
    stageB(0, 0);
    quantX();          // waits qb0 (B0 DMAs keep flowing)
    writeA(0, 0);
    loadX(1);          // qb1 in flight (drained at step-0 sync; one-time)
    __syncthreads();

    // ---- main: 8 K-steps, one __syncthreads each, full double-buffer -----
    // (R4's verified loop; q4 holds qb s>>1 at entry to step s)
#pragma unroll
    for (int s = 0; s < 8; ++s) {
        int cur = s & 1, nxt = cur ^ 1;
        if (s < 7) stageB(nxt, s + 1);
        if ((s & 1) == 0) {
            if (s < 7) writeA(nxt, 1);               // half1 of current block
        } else if (s < 7) {
            quantX();                                // block (s+1)/2
            writeA(nxt, 0);                          // its half0
            if (s < 5) loadX((s + 3) / 2);           // next X, ~1.5 steps ahead
        }
        mfmaStep(cur);
        if (s < 7) __syncthreads();
    }

    // ---- epilogue: C/D layout col=lane&15, row=(lane>>4)*4+e --------------
#pragma unroll
    for (int ni = 0; ni < 2; ++ni) {
        int col = wn * 32 + ni * 16 + lr;
#pragma unroll
        for (int mi = 0; mi < 4; ++mi) {
            int r0 = mi * 16 + lg * 4;
#pragma unroll
            for (int e = 0; e < 4; ++e)
                Cb[(size_t)(r0 + e) * N + col] = acc[mi][ni][e] + bv[ni];
        }
    }
}

// ---------------------------------------------------------------------------
extern "C" void kernel_launch(void* const* d_in, const int* in_sizes, int n_in,
                              void* d_out, int out_size, void* d_ws, size_t ws_size,
                              hipStream_t stream) {
    const float* X    = (const float*)d_in[0];
    const float* W    = (const float*)d_in[1];
    const float* bias = (const float*)d_in[2];
    const int K = 512;
    const int M = in_sizes[0] / K;   // 65536

    __hip_bfloat16* Wt = (__hip_bfloat16*)d_ws;   // 512*512*2 = 512 KB

    wdq_kernel<<<dim3(512), dim3(128), 0, stream>>>(W, Wt);
    fused_gemm<<<dim3((M / 64) * (512 / 256)), dim3(512), 0, stream>>>(
        X, Wt, bias, (float*)d_out, M);
}

// Round 21
// 84.805 us; speedup vs baseline: 1.0352x; 1.0352x over previous
//
#include <hip/hip_runtime.h>
#include <hip/hip_bf16.h>

typedef __attribute__((ext_vector_type(4))) float  floatx4;
typedef __attribute__((ext_vector_type(2))) float  floatx2;
typedef __attribute__((ext_vector_type(8))) __bf16 bf16x8;

#define FP8_MAX 448.0f

// HW OCP e4m3fn round-trip (RNE), matches ml_dtypes float8_e4m3fn for |v|<=448
__device__ __forceinline__ floatx2 fp8_qdq2(float a, float b) {
    int p = __builtin_amdgcn_cvt_pk_fp8_f32(a, b, 0, false);
    return __builtin_amdgcn_cvt_pk_f32_fp8(p, false);
}

__device__ __forceinline__ unsigned int f2bf(float f) {
    union { __hip_bfloat16 h; unsigned short u; } cv;
    cv.h = __float2bfloat16(f);
    return (unsigned int)cv.u;
}

__device__ __forceinline__ void async_copy16(void* lds, const void* g) {
    __builtin_amdgcn_global_load_lds(
        (const __attribute__((address_space(1))) unsigned int*)g,
        (__attribute__((address_space(3))) unsigned int*)lds, 16, 0, 0);
}

// ---------------------------------------------------------------------------
// Kernel 1: dequantize W [D=512][F=512] (quant blocks of 128 along F),
//           write transposed bf16 Wt [F=512][D=512].
__global__ void wdq_kernel(const float* __restrict__ W,
                           __hip_bfloat16* __restrict__ Wt) {
    const int D = 512, F = 512;
    int d = blockIdx.x;
    int t = threadIdx.x;
    float4 v = *reinterpret_cast<const float4*>(W + (size_t)d * F + t * 4);
    float am = fmaxf(fmaxf(fabsf(v.x), fabsf(v.y)), fmaxf(fabsf(v.z), fabsf(v.w)));
#pragma unroll
    for (int s = 16; s >= 1; s >>= 1) am = fmaxf(am, __shfl_xor(am, s));
    float scale = fmaxf(am, 1e-4f) / FP8_MAX;
    floatx2 d01 = fp8_qdq2(v.x / scale, v.y / scale);
    floatx2 d23 = fp8_qdq2(v.z / scale, v.w / scale);
    int f0 = t * 4;
    Wt[(size_t)(f0 + 0) * D + d] = __float2bfloat16(d01[0] * scale);
    Wt[(size_t)(f0 + 1) * D + d] = __float2bfloat16(d01[1] * scale);
    Wt[(size_t)(f0 + 2) * D + d] = __float2bfloat16(d23[0] * scale);
    Wt[(size_t)(f0 + 3) * D + d] = __float2bfloat16(d23[1] * scale);
}

// ---------------------------------------------------------------------------
// Kernel 2 (fused): SESSION-TERMINAL KERNEL (best measured: 86.6 us, R19).
// Structural plateau after 20 rounds: per CU per K-step, LDS traffic
// (~208 KB ≈ 2100 cyc) dominates matrix work (~310 cyc); escapes all
// measured/reasoned dead (bigger wave tile -> VGPR wall; reg-B -> L2
// refetch wall R11; reg-A -> scatter wall R8; BK=128 -> occupancy wall;
// 8-phase interleave -> unreconstructable safely headless, partial ports
// negative R3/R13). Geometry: BM=64/BN=256/BK=64, 256 thr = 4 waves (1x4),
// wave tile 64x64, acc 4x4 = 32 MFMA/wave/step, 8 steps, one
// {vmcnt(N); lgkmcnt(0); barrier} each. LDS 80 KB -> 2 blocks/CU.
// FIFO trace (per wave, 8 VMEM ops per stageB / per loadX):
//   post-prologue queue: [X1.8]
//   t0: +B1.8 +X2.8 -> boundary(8) retires X1+B1, floats X2
//   t1: +B2.8        -> boundary(0) drains (X2 in flight ~1.5 steps)
//   t2: +B3.8 +X3.8 -> boundary(8) retires B3, floats X3
//   t3: +B4.8        -> boundary(0) drains
//   t4..t6: +B.8     -> boundary(0)
// Every quantX consumes X already retired at a prior boundary.
// XOR slot swizzle both-sides (slot ^= row&7): 0 bank conflicts.
__global__ __launch_bounds__(256, 2) void fused_gemm(
        const float* __restrict__ X,             // [M][512] f32
        const __hip_bfloat16* __restrict__ Wt,   // [512 f][512 k] bf16
        const float* __restrict__ bias,          // [512]
        float* __restrict__ C, int M) {
    const int K = 512, N = 512;
    __shared__ char As[2][8192];    // [64 r][8 slot16B], swizzled
    __shared__ char Bs[2][32768];   // [256 f][8 slot16B], swizzled

    // XCD-chunked bijective swizzle (grid 2048 % 8 == 0): tN pair of each tM
    // adjacent on one XCD -> X panel fetched from HBM once.
    int bx   = blockIdx.x;
    int tile = (bx & 7) * (gridDim.x >> 3) + (bx >> 3);
    int tN   = tile & 1;             // N-panel of 256
    int tM   = tile >> 1;            // M-tile of 64 rows

    int tid = threadIdx.x, wid = tid >> 6, lane = tid & 63;
    int wn = wid;                    // wave grid 1(M) x 4(N)
    int lr = lane & 15, lg = lane >> 4;
    int ar = tid >> 2, aq = tid & 3; // A-quant: 4 thr/row, 32 f32 each

    const float* Xb = X + (size_t)(tM * 64) * K;
    const char* Wb  = (const char*)(Wt + (size_t)tN * 256 * K);
    float* Cb = C + (size_t)(tM * 64) * N + tN * 256;

    float4 vA[8], vB[8];   // two X stashes (32 f32 each)
    uint4  q4[4];          // quantized bf16 (32 elems = 4 slots)
    floatx4 acc[4][4] = {};

    auto loadX = [&](float4 (&v)[8], int qb) {
        const float* src = Xb + (size_t)ar * K + qb * 128 + aq * 32;
#pragma unroll
        for (int j = 0; j < 8; ++j)
            v[j] = *reinterpret_cast<const float4*>(src + j * 4);
    };
    auto quantX = [&](const float4 (&v)[8]) {
        float am = 0.f;
#pragma unroll
        for (int j = 0; j < 8; ++j)
            am = fmaxf(am, fmaxf(fmaxf(fabsf(v[j].x), fabsf(v[j].y)),
                                 fmaxf(fabsf(v[j].z), fabsf(v[j].w))));
        am = fmaxf(am, __shfl_xor(am, 1));
        am = fmaxf(am, __shfl_xor(am, 2));
        am = fmaxf(am, 1e-4f);
        float scale = am / FP8_MAX;     // exact reference scale (IEEE div)
        float inv   = FP8_MAX / am;
#pragma unroll
        for (int n = 0; n < 4; ++n) {
            floatx2 a0 = fp8_qdq2(v[2*n].x*inv,   v[2*n].y*inv);
            floatx2 a1 = fp8_qdq2(v[2*n].z*inv,   v[2*n].w*inv);
            floatx2 a2 = fp8_qdq2(v[2*n+1].x*inv, v[2*n+1].y*inv);
            floatx2 a3 = fp8_qdq2(v[2*n+1].z*inv, v[2*n+1].w*inv);
            q4[n].x = f2bf(a0[0]*scale) | (f2bf(a0[1]*scale) << 16);
            q4[n].y = f2bf(a1[0]*scale) | (f2bf(a1[1]*scale) << 16);
            q4[n].z = f2bf(a2[0]*scale) | (f2bf(a2[1]*scale) << 16);
            q4[n].w = f2bf(a3[0]*scale) | (f2bf(a3[1]*scale) << 16);
        }
    };
    auto writeA = [&](int buf, int hb) {   // k-half hb of q4 -> As[buf]
        if ((aq >> 1) == hb) {
#pragma unroll
            for (int n = 0; n < 4; ++n) {
                int slot = (aq & 1) * 4 + n;
                *reinterpret_cast<uint4*>(
                    As[buf] + ar * 128 + ((slot ^ (ar & 7)) << 4)) = q4[n];
            }
        }
    };
    auto stageB = [&](int buf, int step) {   // 32 x 1KB chunks, 8/wave
        const char* base = Wb + step * 128;
#pragma unroll
        for (int cc = 0; cc < 8; ++cc) {
            int c  = wid * 8 + cc;
            int rr = c * 8 + (lane >> 3);
            int d  = lane & 7;
            async_copy16(Bs[buf] + c * 1024,
                         base + (size_t)rr * (K * 2) + ((d ^ (rr & 7)) << 4));
        }
    };
    auto mfmaStep = [&](int buf) {
#pragma unroll
        for (int ks = 0; ks < 2; ++ks) {
            int q = (ks << 2) | lg;
            bf16x8 a[4], b[4];
#pragma unroll
            for (int mi = 0; mi < 4; ++mi) {
                int r = mi * 16 + lr;
                a[mi] = *reinterpret_cast<const bf16x8*>(
                    As[buf] + r * 128 + ((q ^ (r & 7)) << 4));
            }
#pragma unroll
            for (int ni = 0; ni < 4; ++ni) {
                int f = wn * 64 + ni * 16 + lr;
                b[ni] = *reinterpret_cast<const bf16x8*>(
                    Bs[buf] + f * 128 + ((q ^ (f & 7)) << 4));
            }
#pragma unroll
            for (int mi = 0; mi < 4; ++mi)
#pragma unroll
                for (int ni = 0; ni < 4; ++ni)
                    acc[mi][ni] = __builtin_amdgcn_mfma_f32_16x16x32_bf16(
                        a[mi], b[ni], acc[mi][ni], 0, 0, 0);
        }
    };
    auto boundary = [&](int n) {   // counted wait + barrier
        if (n == 8) asm volatile("s_waitcnt vmcnt(8)" ::: "memory");
        else        asm volatile("s_waitcnt vmcnt(0)" ::: "memory");
        asm volatile("s_waitcnt lgkmcnt(0)" ::: "memory");
        __builtin_amdgcn_s_barrier();
    };

    // ---- prologue: issue bias,X0,B0,X1 THEN quant (X0 wait overlaps B0) ---
    float bv[4];
#pragma unroll
    for (int ni = 0; ni < 4; ++ni)
        bv[ni] = bias[tN * 256 + wn * 64 + ni * 16 + lr];
    loadX(vA, 0);
    stageB(0, 0);
    __builtin_amdgcn_sched_barrier(0);   // pin: B0 before X1 (FIFO order)
    loadX(vB, 1);
    quantX(vA);                 // auto-wait retires bias+X0; B0+X1 float
    writeA(0, 0);               // half0 of qb0 -> As[0] (step 0)
    boundary(8);                // [B0.8][X1.8] -> drain B0, float X1

    // ---- main: 8 steps; As/Bs double-buffered; quant at odd t -------------
    // t0: stage B1, load qb2->vA,  MFMA(buf0), writeA(As[1], qb0 half1)
    stageB(1, 1);
    __builtin_amdgcn_sched_barrier(0);   // pin: B1 before X2
    loadX(vA, 2);
    writeA(1, 1);
    mfmaStep(0);
    boundary(8);     // [X1.8][B1.8][X2.8] -> drain X1+B1, float X2

    // t1: stage B2, quant qb1 (vB retired), MFMA(buf1), writeA(As[0], h0)
    stageB(0, 2);
    quantX(vB);
    writeA(0, 0);
    mfmaStep(1);
    boundary(0);     // [X2.8][B2.8] -> drain both (X2 in flight ~1.5 steps)

    // t2: stage B3, load qb3->vB, MFMA(buf0), writeA(As[1], qb1 half1)
    stageB(1, 3);
    __builtin_amdgcn_sched_barrier(0);   // pin: B3 before X3
    loadX(vB, 3);
    writeA(1, 1);
    mfmaStep(0);
    boundary(8);     // [B3.8][X3.8] -> drain B3, float X3

    // t3: stage B4, quant qb2 (vA retired at t1), MFMA(buf1), writeA h0
    stageB(0, 4);
    quantX(vA);
    writeA(0, 0);
    mfmaStep(1);
    boundary(0);     // [X3.8][B4.8] -> drain both

    // t4: stage B5, MFMA(buf0), writeA(As[1], qb2 half1)
    stageB(1, 5);
    writeA(1, 1);
    mfmaStep(0);
    boundary(0);

    // t5: stage B6, quant qb3 (vB retired at t3), MFMA(buf1), writeA h0
    stageB(0, 6);
    quantX(vB);
    writeA(0, 0);
    mfmaStep(1);
    boundary(0);

    // t6: stage B7, MFMA(buf0), writeA(As[1], qb3 half1)
    stageB(1, 7);
    writeA(1, 1);
    mfmaStep(0);
    boundary(0);

    // t7: MFMA(buf1), no boundary
    mfmaStep(1);

    // ---- epilogue: C/D layout col=lane&15, row=(lane>>4)*4+e --------------
#pragma unroll
    for (int ni = 0; ni < 4; ++ni) {
        int col = wn * 64 + ni * 16 + lr;
#pragma unroll
        for (int mi = 0; mi < 4; ++mi) {
            int r0 = mi * 16 + lg * 4;
#pragma unroll
            for (int e = 0; e < 4; ++e)
                Cb[(size_t)(r0 + e) * N + col] = acc[mi][ni][e] + bv[ni];
        }
    }
}

// ---------------------------------------------------------------------------
extern "C" void kernel_launch(void* const* d_in, const int* in_sizes, int n_in,
                              void* d_out, int out_size, void* d_ws, size_t ws_size,
                              hipStream_t stream) {
    const float* X    = (const float*)d_in[0];
    const float* W    = (const float*)d_in[1];
    const float* bias = (const float*)d_in[2];
    const int K = 512;
    const int M = in_sizes[0] / K;   // 65536

    __hip_bfloat16* Wt = (__hip_bfloat16*)d_ws;   // 512*512*2 = 512 KB

    wdq_kernel<<<dim3(512), dim3(128), 0, stream>>>(W, Wt);
    fused_gemm<<<dim3((M / 64) * (512 / 256)), dim3(256), 0, stream>>>(
        X, Wt, bias, (float*)d_out, M);
}